// Round 3
// baseline (208.827 us; speedup 1.0000x reference)
//
#include <hip/hip_runtime.h>

typedef unsigned int uint;
typedef unsigned short ushort;
typedef __attribute__((ext_vector_type(8))) short bf16x8;
typedef __attribute__((ext_vector_type(4))) float f32x4;

namespace {
constexpr int kS = 2048;
constexpr int kD = 512;
constexpr int kH = 8;
constexpr int kBand = 16;
}  // namespace

static __device__ __forceinline__ ushort f2bf(float f) {
  uint u = __builtin_bit_cast(uint, f);
  u = (u + 0x7fffu + ((u >> 16) & 1u)) >> 16;  // RNE
  return (ushort)u;
}

// 8 fp32 -> bf16x8 via v_cvt_pk_bf16_f32 (RNE; bit-identical to f2bf).
static __device__ __forceinline__ bf16x8 cvt8(f32x4 lo, f32x4 hi) {
  uint4 r;
  asm("v_cvt_pk_bf16_f32 %0, %1, %2" : "=v"(r.x) : "v"(lo[0]), "v"(lo[1]));
  asm("v_cvt_pk_bf16_f32 %0, %1, %2" : "=v"(r.y) : "v"(lo[2]), "v"(lo[3]));
  asm("v_cvt_pk_bf16_f32 %0, %1, %2" : "=v"(r.z) : "v"(hi[0]), "v"(hi[1]));
  asm("v_cvt_pk_bf16_f32 %0, %1, %2" : "=v"(r.w) : "v"(hi[2]), "v"(hi[3]));
  return __builtin_bit_cast(bf16x8, r);
}

// ---------------------------------------------------------------------------
// Prep: weight transpose only. 256 blocks: WT[z][n][k] = bf16(W[z][k][n]).
// ---------------------------------------------------------------------------
__global__ __launch_bounds__(256) void prep_kernel(
    const float* __restrict__ wq, const float* __restrict__ wk,
    const float* __restrict__ wv, const float* __restrict__ wo,
    ushort* __restrict__ WT) {
  __shared__ float Ws[64][65];
  const int w = blockIdx.x;  // 0..255
  const int tid = threadIdx.x;
  const int z = w >> 6;
  const float* W = z == 0 ? wq : (z == 1 ? wk : (z == 2 ? wv : wo));
  ushort* T = WT + (size_t)z * kD * kD;
  const int kt = ((w >> 3) & 7) * 64, nt = (w & 7) * 64;
  const int r = tid >> 2, c0 = (tid & 3) * 16;
#pragma unroll
  for (int i = 0; i < 4; ++i) {
    const float4 x =
        *(const float4*)(W + (size_t)(kt + r) * kD + nt + c0 + i * 4);
    Ws[r][c0 + i * 4 + 0] = x.x;
    Ws[r][c0 + i * 4 + 1] = x.y;
    Ws[r][c0 + i * 4 + 2] = x.z;
    Ws[r][c0 + i * 4 + 3] = x.w;
  }
  __syncthreads();
  const int n = tid >> 2, k0 = (tid & 3) * 16;
  alignas(16) ushort tmp[16];
#pragma unroll
  for (int i = 0; i < 16; ++i) tmp[i] = f2bf(Ws[k0 + i][n]);
  ushort* dst = T + (size_t)(nt + n) * kD + kt + k0;
  *(uint4*)(dst + 0) = *(const uint4*)&tmp[0];
  *(uint4*)(dst + 8) = *(const uint4*)&tmp[8];
}

// ---------------------------------------------------------------------------
// QKV GEMM, barrier-free: one wave per 64x64 output tile, NO LDS in K-loop,
// NO s_barrier. A (fp32 q/k/v) and B (bf16 WT, 512 KB/mode -> L2-resident)
// fragments read directly from global; A converted in-reg via cvt_pk.
// Fully-unrolled 16-step K-loop with 1-step register prefetch; all K-step
// offsets fold into the 13-bit global_load immediate. Latency hidden by
// 8 independent wave-streams/CU (no lockstep convoy).
// grid 3072: lin -> xcd(lin&7) | col(j&7) | rlin = xcd+8*(j>>3) in [0,384):
// mode = rlin>>7, row0 = (rlin&127)*64. The 8 col-tiles of a row-slab share
// an XCD and a dispatch window -> A row-slab is HBM-fetched once, L2-hit 7x.
// ---------------------------------------------------------------------------
__global__ __launch_bounds__(64) void gemm_qkv(
    const float* __restrict__ q, const float* __restrict__ k,
    const float* __restrict__ v, const ushort* __restrict__ WT,
    const float* __restrict__ bq, const float* __restrict__ bk,
    const float* __restrict__ bv, ushort* __restrict__ Qp,
    ushort* __restrict__ Kp, ushort* __restrict__ VT) {
  __shared__ alignas(16) ushort Tl[64 * 72];  // epilogue transpose only

  const int lane = threadIdx.x, l15 = lane & 15, qd = lane >> 4;
  const int lin = blockIdx.x;
  const int xcd = lin & 7, j = lin >> 3;
  const int rlin = xcd + 8 * (j >> 3);  // 0..383
  const int col = (j & 7) * 64;
  const int mode = rlin >> 7;           // 0..2
  const int row0 = (rlin & 127) * 64;

  const float* Ab = mode == 0 ? q : (mode == 1 ? k : v);
  const float* bias = mode == 0 ? bq : (mode == 1 ? bk : bv);
  const ushort* BT = WT + (size_t)mode * kD * kD;

  const float* pAm[4];
  const ushort* pBn[4];
#pragma unroll
  for (int mi = 0; mi < 4; ++mi)
    pAm[mi] = Ab + (size_t)(row0 + mi * 16 + l15) * kD + qd * 8;
#pragma unroll
  for (int ni = 0; ni < 4; ++ni)
    pBn[ni] = BT + (size_t)(col + ni * 16 + l15) * kD + qd * 8;

  f32x4 acc[4][4];
#pragma unroll
  for (int mi = 0; mi < 4; ++mi)
#pragma unroll
    for (int ni = 0; ni < 4; ++ni) acc[mi][ni] = (f32x4)(0.f);

  f32x4 an[8];
  bf16x8 bn[4];
#pragma unroll
  for (int mi = 0; mi < 4; ++mi) {
    an[2 * mi] = *(const f32x4*)(pAm[mi]);
    an[2 * mi + 1] = *(const f32x4*)(pAm[mi] + 4);
  }
#pragma unroll
  for (int ni = 0; ni < 4; ++ni) bn[ni] = *(const bf16x8*)(pBn[ni]);

#pragma unroll
  for (int it = 0; it < 16; ++it) {
    bf16x8 af[4], bu[4];
#pragma unroll
    for (int mi = 0; mi < 4; ++mi) af[mi] = cvt8(an[2 * mi], an[2 * mi + 1]);
#pragma unroll
    for (int ni = 0; ni < 4; ++ni) bu[ni] = bn[ni];
    if (it < 15) {
      const int kk = (it + 1) * 32;
#pragma unroll
      for (int mi = 0; mi < 4; ++mi) {
        an[2 * mi] = *(const f32x4*)(pAm[mi] + kk);
        an[2 * mi + 1] = *(const f32x4*)(pAm[mi] + kk + 4);
      }
#pragma unroll
      for (int ni = 0; ni < 4; ++ni) bn[ni] = *(const bf16x8*)(pBn[ni] + kk);
    }
#pragma unroll
    for (int mi = 0; mi < 4; ++mi)
#pragma unroll
      for (int ni = 0; ni < 4; ++ni)
        acc[mi][ni] = __builtin_amdgcn_mfma_f32_16x16x32_bf16(
            af[mi], bu[ni], acc[mi][ni], 0, 0, 0);
  }

  float bcol[4];
#pragma unroll
  for (int ni = 0; ni < 4; ++ni) bcol[ni] = bias[col + ni * 16 + l15];

  // Per-wave 64x64 transpose through LDS (stride 72), no cross-wave sync.
  if (mode <= 1) {  // place [token_local][d_local]
#pragma unroll
    for (int mi = 0; mi < 4; ++mi)
#pragma unroll
      for (int ni = 0; ni < 4; ++ni)
#pragma unroll
        for (int r = 0; r < 4; ++r)
          Tl[(mi * 16 + qd * 4 + r) * 72 + ni * 16 + l15] =
              f2bf(acc[mi][ni][r] + bcol[ni]);
  } else {  // mode 2: place [d_local][token_local]
#pragma unroll
    for (int mi = 0; mi < 4; ++mi)
#pragma unroll
      for (int ni = 0; ni < 4; ++ni)
#pragma unroll
        for (int r = 0; r < 4; ++r)
          Tl[(ni * 16 + l15) * 72 + mi * 16 + qd * 4 + r] =
              f2bf(acc[mi][ni][r] + bcol[ni]);
  }
  asm volatile("s_waitcnt lgkmcnt(0)" ::: "memory");  // wave-local visibility

  const ushort* Trow = &Tl[lane * 72];
  if (mode <= 1) {
    ushort* C = (mode == 0) ? Qp : Kp;
    ushort* dst = C + (size_t)(row0 + lane) * kD + col;
#pragma unroll
    for (int c = 0; c < 8; ++c)
      *(uint4*)(dst + c * 8) = *(const uint4*)(Trow + c * 8);
  } else {
    const int n_g = col + lane;
    const int h = n_g >> 6, d = n_g & 63;
    const int b = row0 >> 11, ss = row0 & (kS - 1);
    ushort* dst = VT + ((size_t)(b * kH + h) * 64 + d) * kS + ss;
#pragma unroll
    for (int c = 0; c < 8; ++c)
      *(uint4*)(dst + c * 8) = *(const uint4*)(Trow + c * 8);
  }
}

// ---------------------------------------------------------------------------
// MFMA banded attention, 32-query tiles. One wave per tile per (b,h).
// grid (64,32) = 2048 waves. K window per tile: [q0-16, q0+48) = 64 keys.
// ---------------------------------------------------------------------------
__global__ __launch_bounds__(64, 2) void attn_kernel(
    const ushort* __restrict__ Qp, const ushort* __restrict__ Kp,
    const ushort* __restrict__ VT, ushort* __restrict__ Ob) {
  __shared__ alignas(16) ushort Pl[32 * 72];  // P scatter; reused for O xpose

  const int lane = threadIdx.x, l15 = lane & 15, qd = lane >> 4;
  const int bh = blockIdx.y, b = bh >> 3, h = bh & 7;
  const int q0 = blockIdx.x * 32;
  const int colA = h * 64;

  bf16x8 qf[2][2], kf[4][2];
#pragma unroll
  for (int mi = 0; mi < 2; ++mi) {
    const size_t base =
        ((size_t)b * kS + q0 + mi * 16 + l15) * kD + colA + qd * 8;
#pragma unroll
    for (int kc = 0; kc < 2; ++kc)
      qf[mi][kc] = *(const bf16x8*)&Qp[base + kc * 32];
  }
#pragma unroll
  for (int ni = 0; ni < 4; ++ni) {
    int key = q0 - kBand + ni * 16 + l15;
    key = key < 0 ? 0 : (key > kS - 1 ? kS - 1 : key);  // clamp; masked below
    const size_t base = ((size_t)b * kS + key) * kD + colA + qd * 8;
#pragma unroll
    for (int kc = 0; kc < 2; ++kc)
      kf[ni][kc] = *(const bf16x8*)&Kp[base + kc * 32];
  }

  f32x4 S[2][4];
#pragma unroll
  for (int mi = 0; mi < 2; ++mi)
#pragma unroll
    for (int ni = 0; ni < 4; ++ni) S[mi][ni] = (f32x4)(0.f);
#pragma unroll
  for (int mi = 0; mi < 2; ++mi)
#pragma unroll
    for (int ni = 0; ni < 4; ++ni)
#pragma unroll
      for (int kc = 0; kc < 2; ++kc)
        S[mi][ni] = __builtin_amdgcn_mfma_f32_16x16x32_bf16(
            qf[mi][kc], kf[ni][kc], S[mi][ni], 0, 0, 0);

#pragma unroll
  for (int mi = 0; mi < 2; ++mi)
#pragma unroll
    for (int ni = 0; ni < 4; ++ni)
#pragma unroll
      for (int r = 0; r < 4; ++r) {
        const int q_local = mi * 16 + qd * 4 + r;
        const int key_local = ni * 16 + l15;
        const int key = q0 - kBand + key_local;
        const int dlt = key_local - q_local;
        const bool ok = (dlt >= 0) && (dlt <= 32) && (key >= 0) && (key < kS);
        S[mi][ni][r] = ok ? S[mi][ni][r] * 0.125f : -3.0e38f;
      }

  float inv[2][4];
#pragma unroll
  for (int mi = 0; mi < 2; ++mi)
#pragma unroll
    for (int r = 0; r < 4; ++r) {
      float m = S[mi][0][r];
#pragma unroll
      for (int ni = 1; ni < 4; ++ni) m = fmaxf(m, S[mi][ni][r]);
      m = fmaxf(m, __shfl_xor(m, 1));
      m = fmaxf(m, __shfl_xor(m, 2));
      m = fmaxf(m, __shfl_xor(m, 4));
      m = fmaxf(m, __shfl_xor(m, 8));
      float s = 0.f;
#pragma unroll
      for (int ni = 0; ni < 4; ++ni) {
        const float e = __expf(S[mi][ni][r] - m);
        S[mi][ni][r] = e;
        s += e;
      }
      s += __shfl_xor(s, 1);
      s += __shfl_xor(s, 2);
      s += __shfl_xor(s, 4);
      s += __shfl_xor(s, 8);
      inv[mi][r] = 1.f / s;
    }

  // P -> LDS (C-layout scatter, stride 72), read back in A-layout
#pragma unroll
  for (int mi = 0; mi < 2; ++mi)
#pragma unroll
    for (int ni = 0; ni < 4; ++ni)
#pragma unroll
      for (int r = 0; r < 4; ++r)
        Pl[(mi * 16 + qd * 4 + r) * 72 + ni * 16 + l15] = f2bf(S[mi][ni][r]);
  __syncthreads();

  f32x4 O[2][4];
#pragma unroll
  for (int mi = 0; mi < 2; ++mi)
#pragma unroll
    for (int nt = 0; nt < 4; ++nt) O[mi][nt] = (f32x4)(0.f);

#pragma unroll
  for (int kc = 0; kc < 2; ++kc) {
    bf16x8 pf[2], vfr[4];
#pragma unroll
    for (int mi = 0; mi < 2; ++mi)
      pf[mi] = *(const bf16x8*)&Pl[(mi * 16 + l15) * 72 + kc * 32 + qd * 8];
    int kb0 = q0 - kBand + kc * 32 + qd * 8;
    kb0 = kb0 < 0 ? 0 : (kb0 > kS - 8 ? kS - 8 : kb0);  // clamp; P=0 there
#pragma unroll
    for (int nt = 0; nt < 4; ++nt)
      vfr[nt] =
          *(const bf16x8*)&VT[((size_t)bh * 64 + nt * 16 + l15) * kS + kb0];
#pragma unroll
    for (int mi = 0; mi < 2; ++mi)
#pragma unroll
      for (int nt = 0; nt < 4; ++nt)
        O[mi][nt] = __builtin_amdgcn_mfma_f32_16x16x32_bf16(pf[mi], vfr[nt],
                                                            O[mi][nt], 0, 0, 0);
  }

  // O transpose through LDS (reuse Pl; same-wave DS ops are in-order)
#pragma unroll
  for (int mi = 0; mi < 2; ++mi)
#pragma unroll
    for (int nt = 0; nt < 4; ++nt)
#pragma unroll
      for (int r = 0; r < 4; ++r)
        Pl[(mi * 16 + qd * 4 + r) * 72 + nt * 16 + l15] =
            f2bf(O[mi][nt][r] * inv[mi][r]);
  asm volatile("s_waitcnt lgkmcnt(0)" ::: "memory");

  // 32 rows x 64 cols: 2 lanes per row, 64B each.
  const int row = lane >> 1, half = lane & 1;
  ushort* dst = Ob + ((size_t)b * kS + q0 + row) * kD + colA + half * 32;
  const ushort* Trow = &Pl[row * 72 + half * 32];
#pragma unroll
  for (int c = 0; c < 4; ++c)
    *(uint4*)(dst + c * 8) = *(const uint4*)(Trow + c * 8);
}

// ---------------------------------------------------------------------------
// Out-projection GEMM, barrier-free: one wave per 64x64 tile, no LDS at all.
// A = Ob (bf16) direct, B = WTo (L2-resident) direct, fp32 direct stores.
// grid 1024.
// ---------------------------------------------------------------------------
__global__ __launch_bounds__(64) void gemm_out(
    const ushort* __restrict__ Ab, const ushort* __restrict__ BT,
    const float* __restrict__ bias, float* __restrict__ outp) {
  const int lane = threadIdx.x, l15 = lane & 15, qd = lane >> 4;
  const int lin = blockIdx.x;
  const int xcd = lin & 7, j = lin >> 3;        // j 0..127
  const int row0 = (xcd + 8 * (j >> 3)) * 64;   // 0..8128
  const int col = (j & 7) * 64;

  const ushort* pAm[4];
  const ushort* pBn[4];
#pragma unroll
  for (int mi = 0; mi < 4; ++mi)
    pAm[mi] = Ab + (size_t)(row0 + mi * 16 + l15) * kD + qd * 8;
#pragma unroll
  for (int ni = 0; ni < 4; ++ni)
    pBn[ni] = BT + (size_t)(col + ni * 16 + l15) * kD + qd * 8;

  f32x4 acc[4][4];
#pragma unroll
  for (int mi = 0; mi < 4; ++mi)
#pragma unroll
    for (int ni = 0; ni < 4; ++ni) acc[mi][ni] = (f32x4)(0.f);

  bf16x8 an[4], bn[4];
#pragma unroll
  for (int mi = 0; mi < 4; ++mi) an[mi] = *(const bf16x8*)(pAm[mi]);
#pragma unroll
  for (int ni = 0; ni < 4; ++ni) bn[ni] = *(const bf16x8*)(pBn[ni]);

#pragma unroll
  for (int it = 0; it < 16; ++it) {
    bf16x8 af[4], bu[4];
#pragma unroll
    for (int mi = 0; mi < 4; ++mi) af[mi] = an[mi];
#pragma unroll
    for (int ni = 0; ni < 4; ++ni) bu[ni] = bn[ni];
    if (it < 15) {
      const int kk = (it + 1) * 32;
#pragma unroll
      for (int mi = 0; mi < 4; ++mi) an[mi] = *(const bf16x8*)(pAm[mi] + kk);
#pragma unroll
      for (int ni = 0; ni < 4; ++ni) bn[ni] = *(const bf16x8*)(pBn[ni] + kk);
    }
#pragma unroll
    for (int mi = 0; mi < 4; ++mi)
#pragma unroll
      for (int ni = 0; ni < 4; ++ni)
        acc[mi][ni] = __builtin_amdgcn_mfma_f32_16x16x32_bf16(
            af[mi], bu[ni], acc[mi][ni], 0, 0, 0);
  }

#pragma unroll
  for (int ni = 0; ni < 4; ++ni) {
    const int n_g = col + ni * 16 + l15;
    const float bc = bias[n_g];
#pragma unroll
    for (int mi = 0; mi < 4; ++mi)
#pragma unroll
      for (int r = 0; r < 4; ++r) {
        const int token = row0 + mi * 16 + qd * 4 + r;
        outp[(size_t)token * kD + n_g] = acc[mi][ni][r] + bc;
      }
  }
}

extern "C" void kernel_launch(void* const* d_in, const int* in_sizes, int n_in,
                              void* d_out, int out_size, void* d_ws,
                              size_t ws_size, hipStream_t stream) {
  const float* q = (const float*)d_in[0];
  const float* k = (const float*)d_in[1];
  const float* v = (const float*)d_in[2];
  const float* wq = (const float*)d_in[3];
  const float* bq = (const float*)d_in[4];
  const float* wk = (const float*)d_in[5];
  const float* bk = (const float*)d_in[6];
  const float* wv = (const float*)d_in[7];
  const float* bv = (const float*)d_in[8];
  const float* wo = (const float*)d_in[9];
  const float* bo = (const float*)d_in[10];
  float* out = (float*)d_out;

  // ws (~34 MB), no aliasing.
  const size_t n1 = (size_t)8192 * kD;  // 4M ushorts = 8 MB
  ushort* Qp = (ushort*)d_ws;
  ushort* Kp = Qp + n1;
  ushort* VT = Kp + n1;
  ushort* Ob = VT + n1;
  ushort* WT = Ob + n1;

  prep_kernel<<<dim3(256), 256, 0, stream>>>(wq, wk, wv, wo, WT);
  gemm_qkv<<<dim3(3072), 64, 0, stream>>>(q, k, v, WT, bq, bk, bv, Qp, Kp, VT);
  attn_kernel<<<dim3(kS / 32, 32), 64, 0, stream>>>(Qp, Kp, VT, Ob);
  gemm_out<<<dim3(1024), 64, 0, stream>>>(Ob, WT + (size_t)3 * kD * kD, bo,
                                          out);
}

// Round 4
// 156.508 us; speedup vs baseline: 1.3343x; 1.3343x over previous
//
#include <hip/hip_runtime.h>

typedef unsigned int uint;
typedef unsigned short ushort;
typedef __attribute__((ext_vector_type(8))) short bf16x8;
typedef __attribute__((ext_vector_type(4))) float f32x4;

namespace {
constexpr int kS = 2048;
constexpr int kD = 512;
constexpr int kH = 8;
constexpr int kBand = 16;
}  // namespace

static __device__ __forceinline__ ushort f2bf(float f) {
  uint u = __builtin_bit_cast(uint, f);
  u = (u + 0x7fffu + ((u >> 16) & 1u)) >> 16;  // RNE
  return (ushort)u;
}

// 8 fp32 -> bf16x8 via v_cvt_pk_bf16_f32 (RNE; bit-identical to f2bf).
static __device__ __forceinline__ bf16x8 cvt8(f32x4 lo, f32x4 hi) {
  uint4 r;
  asm("v_cvt_pk_bf16_f32 %0, %1, %2" : "=v"(r.x) : "v"(lo[0]), "v"(lo[1]));
  asm("v_cvt_pk_bf16_f32 %0, %1, %2" : "=v"(r.y) : "v"(lo[2]), "v"(lo[3]));
  asm("v_cvt_pk_bf16_f32 %0, %1, %2" : "=v"(r.z) : "v"(hi[0]), "v"(hi[1]));
  asm("v_cvt_pk_bf16_f32 %0, %1, %2" : "=v"(r.w) : "v"(hi[2]), "v"(hi[3]));
  return __builtin_bit_cast(bf16x8, r);
}

// lgkm-only barrier: all staging is reg->LDS, so no vmcnt drain is needed at
// the workgroup barrier (global loads target private registers only).
#define LGKM_BARRIER \
  asm volatile("s_waitcnt lgkmcnt(0)\n\ts_barrier" ::: "memory")

// ---------------------------------------------------------------------------
// Prep: weight transpose into FRAGMENT-PACKED layout. 256 blocks.
// Element W[k][n] of matrix z lands at:
//   c = n>>6, sub = (n>>4)&3, l = n&15, it = k>>5, qd = (k>>3)&3, e = k&7
//   Bpk[ ((z*8+c)*16 + it)*2048 + (sub*64 + qd*16 + l)*8 + e ]
// so a wave reading fragment (c, sub, it) with per-lane offset lane*16B gets
// B[col=c*64+sub*16+l15][k=it*32+qd*8+e] as one fully-coalesced 1KB burst.
// ---------------------------------------------------------------------------
__global__ __launch_bounds__(256) void prep_kernel(
    const float* __restrict__ wq, const float* __restrict__ wk,
    const float* __restrict__ wv, const float* __restrict__ wo,
    ushort* __restrict__ Bpk) {
  __shared__ float Ws[64][65];
  const int w = blockIdx.x;  // 0..255
  const int tid = threadIdx.x;
  const int z = w >> 6;
  const float* W = z == 0 ? wq : (z == 1 ? wk : (z == 2 ? wv : wo));
  const int kt = ((w >> 3) & 7) * 64, nt = (w & 7) * 64;
  const int r = tid >> 2, c0 = (tid & 3) * 16;
#pragma unroll
  for (int i = 0; i < 4; ++i) {
    const float4 x =
        *(const float4*)(W + (size_t)(kt + r) * kD + nt + c0 + i * 4);
    Ws[r][c0 + i * 4 + 0] = x.x;
    Ws[r][c0 + i * 4 + 1] = x.y;
    Ws[r][c0 + i * 4 + 2] = x.z;
    Ws[r][c0 + i * 4 + 3] = x.w;
  }
  __syncthreads();
  const int nl = tid >> 2, k0 = (tid & 3) * 16;
  alignas(16) ushort tmp[16];
#pragma unroll
  for (int i = 0; i < 16; ++i) tmp[i] = f2bf(Ws[k0 + i][nl]);
  const int ng = nt + nl, kg = kt + k0;
  const int c = ng >> 6, sub = (ng >> 4) & 3, l = ng & 15;
  const int it = kg >> 5, q0 = (kg >> 3) & 3;  // q0 in {0,2}
  ushort* base = Bpk + ((size_t)(z * 8 + c) * 16 + it) * 2048 +
                 (sub * 64 + l) * 8;
  *(uint4*)(base + q0 * 128) = *(const uint4*)&tmp[0];
  *(uint4*)(base + (q0 + 1) * 128) = *(const uint4*)&tmp[8];
}

// ---------------------------------------------------------------------------
// QKV GEMM "A-once / B-direct": 128x256 tiles, 512 threads (8 waves, 2x4).
// A (fp32) staged ONCE per row-slab into a 2-stage bf16 LDS buffer via
// reg-staging (global->VGPR, 3-deep prefetch, cvt_pk, ds_write_b128).
// B read straight from the fragment-packed, L2-resident Bpk into registers
// (2-deep prefetch) -- never staged, never behind a barrier.
// Per-iter barrier is lgkm-only; no vmcnt drain anywhere in the loop.
// LDS A rows use stride 40 ushorts (80B): frag ds_read_b128 is 2-way bank
// aliased (free). Grid 384 = 3 modes x 64 row-tiles x 2 col-groups.
// ---------------------------------------------------------------------------
__global__ __launch_bounds__(512) void gemm_qkv(
    const float* __restrict__ q, const float* __restrict__ k,
    const float* __restrict__ v, const ushort* __restrict__ Bpk,
    const float* __restrict__ bq, const float* __restrict__ bk,
    const float* __restrict__ bv, ushort* __restrict__ Qp,
    ushort* __restrict__ Kp, ushort* __restrict__ VT) {
  __shared__ alignas(16) ushort smem[10240];  // 2 stages x 128 x 40

  const int tid = threadIdx.x;
  const int w = tid >> 6, lane = tid & 63, l15 = lane & 15, qd = lane >> 4;
  const int wr = w >> 2, wc = w & 3;  // wave grid 2x4
  const int blk = blockIdx.x;
  const int rt = blk & 63, mcg = blk >> 6;  // mcg 0..5
  const int mode = mcg >> 1, cg = mcg & 1;
  const int row0 = rt * 128;
  const int colbase = cg * 256 + wc * 64;

  const float* Ab = mode == 0 ? q : (mode == 1 ? k : v);
  const float* bias = mode == 0 ? bq : (mode == 1 ? bk : bv);
  const ushort* pBl =
      Bpk + ((size_t)(mode * 8 + (colbase >> 6)) * 16) * 2048 + lane * 8;

  // A staging map: thread -> (row sr, quarter qh); 1 ds_write_b128/iter.
  const int sr = tid >> 2, qh = tid & 3;
  const float* pAg = Ab + (size_t)(row0 + sr) * kD + qh * 8;
  const uint wIdx = (uint)(sr * 40 + qh * 8);

  f32x4 acc[4][4];
#pragma unroll
  for (int mi = 0; mi < 4; ++mi)
#pragma unroll
    for (int ni = 0; ni < 4; ++ni) acc[mi][ni] = (f32x4)(0.f);

  f32x4 as_[3][2];  // 3-deep A prefetch (slot t%3 holds A(t))
  bf16x8 brr[2][4];
#pragma unroll
  for (int s = 0; s < 3; ++s) {
    as_[s][0] = *(const f32x4*)(pAg + s * 32);
    as_[s][1] = *(const f32x4*)(pAg + s * 32 + 4);
  }
#pragma unroll
  for (int ni = 0; ni < 4; ++ni)
    brr[0][ni] = *(const bf16x8*)(pBl + ni * 512);
  *(bf16x8*)&smem[wIdx] = cvt8(as_[0][0], as_[0][1]);
  LGKM_BARRIER;

#pragma unroll
  for (int it = 0; it < 16; ++it) {
    bf16x8 af[4];
#pragma unroll
    for (int mi = 0; mi < 4; ++mi)
      af[mi] = *(const bf16x8*)&smem[(it & 1) * 5120 +
                                     (wr * 64 + mi * 16 + l15) * 40 + qd * 8];
    if (it < 13) {
      as_[it % 3][0] = *(const f32x4*)(pAg + (it + 3) * 32);
      as_[it % 3][1] = *(const f32x4*)(pAg + (it + 3) * 32 + 4);
    }
    if (it < 15) {
#pragma unroll
      for (int ni = 0; ni < 4; ++ni)
        brr[(it + 1) & 1][ni] =
            *(const bf16x8*)(pBl + (it + 1) * 2048 + ni * 512);
      *(bf16x8*)&smem[((it + 1) & 1) * 5120 + wIdx] =
          cvt8(as_[(it + 1) % 3][0], as_[(it + 1) % 3][1]);
    }
#pragma unroll
    for (int mi = 0; mi < 4; ++mi)
#pragma unroll
      for (int ni = 0; ni < 4; ++ni)
        acc[mi][ni] = __builtin_amdgcn_mfma_f32_16x16x32_bf16(
            af[mi], brr[it & 1][ni], acc[mi][ni], 0, 0, 0);
    if (it < 15) LGKM_BARRIER;
  }

  LGKM_BARRIER;  // protect stage region before per-wave transpose reuse

  float bcol[4];
#pragma unroll
  for (int ni = 0; ni < 4; ++ni) bcol[ni] = bias[colbase + ni * 16 + l15];

  ushort* T = &smem[w * 1280];  // per-wave scratch (<= 1280 ushorts)
  if (mode <= 1) {
    ushort* C = (mode == 0) ? Qp : Kp;
#pragma unroll
    for (int p = 0; p < 4; ++p) {  // 16-col passes, buffer [64][20]
#pragma unroll
      for (int mi = 0; mi < 4; ++mi)
#pragma unroll
        for (int r = 0; r < 4; ++r)
          T[(mi * 16 + qd * 4 + r) * 20 + l15] =
              f2bf(acc[mi][p][r] + bcol[p]);
      asm volatile("s_waitcnt lgkmcnt(0)" ::: "memory");
      ushort* dst = C + (size_t)(row0 + wr * 64 + lane) * kD + colbase + p * 16;
      *(uint4*)dst = *(const uint4*)&T[lane * 20];
      *(uint4*)(dst + 8) = *(const uint4*)&T[lane * 20 + 8];
    }
  } else {  // mode 2: VT[bh*64+d][token], buffer [16][72]
#pragma unroll
    for (int p = 0; p < 4; ++p) {
#pragma unroll
      for (int mi = 0; mi < 4; ++mi)
#pragma unroll
        for (int r = 0; r < 4; ++r)
          T[l15 * 72 + mi * 16 + qd * 4 + r] = f2bf(acc[mi][p][r] + bcol[p]);
      asm volatile("s_waitcnt lgkmcnt(0)" ::: "memory");
      const int rowc = lane >> 2, qt = lane & 3;
      const int colg = colbase + p * 16 + rowc;
      const int h = colg >> 6, d = colg & 63;
      const int t0 = row0 + wr * 64;
      const int b = t0 >> 11, ss = t0 & (kS - 1);
      ushort* dst = VT + ((size_t)(b * kH + h) * 64 + d) * kS + ss + qt * 16;
      *(uint4*)dst = *(const uint4*)&T[rowc * 72 + qt * 16];
      *(uint4*)(dst + 8) = *(const uint4*)&T[rowc * 72 + qt * 16 + 8];
    }
  }
}

// ---------------------------------------------------------------------------
// Out-projection GEMM, same template: 128x128 tiles, 512 threads (4x2 waves),
// bf16 A (Ob) reg-staged (3-deep, no cvt), packed-B direct, fp32 stores.
// Grid 256 = 64 row-tiles x 4 col-groups.
// ---------------------------------------------------------------------------
__global__ __launch_bounds__(512) void gemm_out(
    const ushort* __restrict__ Ab, const ushort* __restrict__ Bpk,
    const float* __restrict__ bias, float* __restrict__ outp) {
  __shared__ alignas(16) ushort smem[10240];

  const int tid = threadIdx.x;
  const int w = tid >> 6, lane = tid & 63, l15 = lane & 15, qd = lane >> 4;
  const int wr = w >> 1, wc = w & 1;  // wave grid 4x2
  const int blk = blockIdx.x;
  const int rt = blk & 63, cb = blk >> 6;  // cb 0..3
  const int row0 = rt * 128;
  const int colbase = cb * 128 + wc * 64;

  const ushort* pBl =
      Bpk + ((size_t)(3 * 8 + (colbase >> 6)) * 16) * 2048 + lane * 8;

  const int sr = tid >> 2, qh = tid & 3;
  const ushort* pAg = Ab + (size_t)(row0 + sr) * kD + qh * 8;
  const uint wIdx = (uint)(sr * 40 + qh * 8);

  f32x4 acc[2][4];
#pragma unroll
  for (int mi = 0; mi < 2; ++mi)
#pragma unroll
    for (int ni = 0; ni < 4; ++ni) acc[mi][ni] = (f32x4)(0.f);

  bf16x8 as_[3];
  bf16x8 brr[2][4];
#pragma unroll
  for (int s = 0; s < 3; ++s) as_[s] = *(const bf16x8*)(pAg + s * 32);
#pragma unroll
  for (int ni = 0; ni < 4; ++ni)
    brr[0][ni] = *(const bf16x8*)(pBl + ni * 512);
  *(bf16x8*)&smem[wIdx] = as_[0];
  LGKM_BARRIER;

#pragma unroll
  for (int it = 0; it < 16; ++it) {
    bf16x8 af[2];
#pragma unroll
    for (int mi = 0; mi < 2; ++mi)
      af[mi] = *(const bf16x8*)&smem[(it & 1) * 5120 +
                                     (wr * 32 + mi * 16 + l15) * 40 + qd * 8];
    if (it < 13) as_[it % 3] = *(const bf16x8*)(pAg + (it + 3) * 32);
    if (it < 15) {
#pragma unroll
      for (int ni = 0; ni < 4; ++ni)
        brr[(it + 1) & 1][ni] =
            *(const bf16x8*)(pBl + (it + 1) * 2048 + ni * 512);
      *(bf16x8*)&smem[((it + 1) & 1) * 5120 + wIdx] = as_[(it + 1) % 3];
    }
#pragma unroll
    for (int mi = 0; mi < 2; ++mi)
#pragma unroll
      for (int ni = 0; ni < 4; ++ni)
        acc[mi][ni] = __builtin_amdgcn_mfma_f32_16x16x32_bf16(
            af[mi], brr[it & 1][ni], acc[mi][ni], 0, 0, 0);
    if (it < 15) LGKM_BARRIER;
  }

#pragma unroll
  for (int ni = 0; ni < 4; ++ni) {
    const int n_g = colbase + ni * 16 + l15;
    const float bc = bias[n_g];
#pragma unroll
    for (int mi = 0; mi < 2; ++mi)
#pragma unroll
      for (int r = 0; r < 4; ++r) {
        const int token = row0 + wr * 32 + mi * 16 + qd * 4 + r;
        outp[(size_t)token * kD + n_g] = acc[mi][ni][r] + bc;
      }
  }
}

// ---------------------------------------------------------------------------
// MFMA banded attention, 32-query tiles. One wave per tile per (b,h).
// grid (64,32) = 2048 waves. K window per tile: [q0-16, q0+48) = 64 keys.
// ---------------------------------------------------------------------------
__global__ __launch_bounds__(64, 2) void attn_kernel(
    const ushort* __restrict__ Qp, const ushort* __restrict__ Kp,
    const ushort* __restrict__ VT, ushort* __restrict__ Ob) {
  __shared__ alignas(16) ushort Pl[32 * 72];  // P scatter; reused for O xpose

  const int lane = threadIdx.x, l15 = lane & 15, qd = lane >> 4;
  const int bh = blockIdx.y, b = bh >> 3, h = bh & 7;
  const int q0 = blockIdx.x * 32;
  const int colA = h * 64;

  bf16x8 qf[2][2], kf[4][2];
#pragma unroll
  for (int mi = 0; mi < 2; ++mi) {
    const size_t base =
        ((size_t)b * kS + q0 + mi * 16 + l15) * kD + colA + qd * 8;
#pragma unroll
    for (int kc = 0; kc < 2; ++kc)
      qf[mi][kc] = *(const bf16x8*)&Qp[base + kc * 32];
  }
#pragma unroll
  for (int ni = 0; ni < 4; ++ni) {
    int key = q0 - kBand + ni * 16 + l15;
    key = key < 0 ? 0 : (key > kS - 1 ? kS - 1 : key);  // clamp; masked below
    const size_t base = ((size_t)b * kS + key) * kD + colA + qd * 8;
#pragma unroll
    for (int kc = 0; kc < 2; ++kc)
      kf[ni][kc] = *(const bf16x8*)&Kp[base + kc * 32];
  }

  f32x4 S[2][4];
#pragma unroll
  for (int mi = 0; mi < 2; ++mi)
#pragma unroll
    for (int ni = 0; ni < 4; ++ni) S[mi][ni] = (f32x4)(0.f);
#pragma unroll
  for (int mi = 0; mi < 2; ++mi)
#pragma unroll
    for (int ni = 0; ni < 4; ++ni)
#pragma unroll
      for (int kc = 0; kc < 2; ++kc)
        S[mi][ni] = __builtin_amdgcn_mfma_f32_16x16x32_bf16(
            qf[mi][kc], kf[ni][kc], S[mi][ni], 0, 0, 0);

#pragma unroll
  for (int mi = 0; mi < 2; ++mi)
#pragma unroll
    for (int ni = 0; ni < 4; ++ni)
#pragma unroll
      for (int r = 0; r < 4; ++r) {
        const int q_local = mi * 16 + qd * 4 + r;
        const int key_local = ni * 16 + l15;
        const int key = q0 - kBand + key_local;
        const int dlt = key_local - q_local;
        const bool ok = (dlt >= 0) && (dlt <= 32) && (key >= 0) && (key < kS);
        S[mi][ni][r] = ok ? S[mi][ni][r] * 0.125f : -3.0e38f;
      }

  float inv[2][4];
#pragma unroll
  for (int mi = 0; mi < 2; ++mi)
#pragma unroll
    for (int r = 0; r < 4; ++r) {
      float m = S[mi][0][r];
#pragma unroll
      for (int ni = 1; ni < 4; ++ni) m = fmaxf(m, S[mi][ni][r]);
      m = fmaxf(m, __shfl_xor(m, 1));
      m = fmaxf(m, __shfl_xor(m, 2));
      m = fmaxf(m, __shfl_xor(m, 4));
      m = fmaxf(m, __shfl_xor(m, 8));
      float s = 0.f;
#pragma unroll
      for (int ni = 0; ni < 4; ++ni) {
        const float e = __expf(S[mi][ni][r] - m);
        S[mi][ni][r] = e;
        s += e;
      }
      s += __shfl_xor(s, 1);
      s += __shfl_xor(s, 2);
      s += __shfl_xor(s, 4);
      s += __shfl_xor(s, 8);
      inv[mi][r] = 1.f / s;
    }

  // P -> LDS (C-layout scatter, stride 72), read back in A-layout
#pragma unroll
  for (int mi = 0; mi < 2; ++mi)
#pragma unroll
    for (int ni = 0; ni < 4; ++ni)
#pragma unroll
      for (int r = 0; r < 4; ++r)
        Pl[(mi * 16 + qd * 4 + r) * 72 + ni * 16 + l15] = f2bf(S[mi][ni][r]);
  __syncthreads();

  f32x4 O[2][4];
#pragma unroll
  for (int mi = 0; mi < 2; ++mi)
#pragma unroll
    for (int nt = 0; nt < 4; ++nt) O[mi][nt] = (f32x4)(0.f);

#pragma unroll
  for (int kc = 0; kc < 2; ++kc) {
    bf16x8 pf[2], vfr[4];
#pragma unroll
    for (int mi = 0; mi < 2; ++mi)
      pf[mi] = *(const bf16x8*)&Pl[(mi * 16 + l15) * 72 + kc * 32 + qd * 8];
    int kb0 = q0 - kBand + kc * 32 + qd * 8;
    kb0 = kb0 < 0 ? 0 : (kb0 > kS - 8 ? kS - 8 : kb0);  // clamp; P=0 there
#pragma unroll
    for (int nt = 0; nt < 4; ++nt)
      vfr[nt] =
          *(const bf16x8*)&VT[((size_t)bh * 64 + nt * 16 + l15) * kS + kb0];
#pragma unroll
    for (int mi = 0; mi < 2; ++mi)
#pragma unroll
      for (int nt = 0; nt < 4; ++nt)
        O[mi][nt] = __builtin_amdgcn_mfma_f32_16x16x32_bf16(pf[mi], vfr[nt],
                                                            O[mi][nt], 0, 0, 0);
  }

  // O transpose through LDS (reuse Pl; same-wave DS ops are in-order)
#pragma unroll
  for (int mi = 0; mi < 2; ++mi)
#pragma unroll
    for (int nt = 0; nt < 4; ++nt)
#pragma unroll
      for (int r = 0; r < 4; ++r)
        Pl[(mi * 16 + qd * 4 + r) * 72 + nt * 16 + l15] =
            f2bf(O[mi][nt][r] * inv[mi][r]);
  asm volatile("s_waitcnt lgkmcnt(0)" ::: "memory");

  // 32 rows x 64 cols: 2 lanes per row, 64B each.
  const int row = lane >> 1, half = lane & 1;
  ushort* dst = Ob + ((size_t)b * kS + q0 + row) * kD + colA + half * 32;
  const ushort* Trow = &Pl[row * 72 + half * 32];
#pragma unroll
  for (int c = 0; c < 4; ++c)
    *(uint4*)(dst + c * 8) = *(const uint4*)(Trow + c * 8);
}

extern "C" void kernel_launch(void* const* d_in, const int* in_sizes, int n_in,
                              void* d_out, int out_size, void* d_ws,
                              size_t ws_size, hipStream_t stream) {
  const float* q = (const float*)d_in[0];
  const float* k = (const float*)d_in[1];
  const float* v = (const float*)d_in[2];
  const float* wq = (const float*)d_in[3];
  const float* bq = (const float*)d_in[4];
  const float* wk = (const float*)d_in[5];
  const float* bk = (const float*)d_in[6];
  const float* wv = (const float*)d_in[7];
  const float* bv = (const float*)d_in[8];
  const float* wo = (const float*)d_in[9];
  const float* bo = (const float*)d_in[10];
  float* out = (float*)d_out;

  // ws (~34 MB), no aliasing.
  const size_t n1 = (size_t)8192 * kD;  // 4M ushorts = 8 MB
  ushort* Qp = (ushort*)d_ws;
  ushort* Kp = Qp + n1;
  ushort* VT = Kp + n1;
  ushort* Ob = VT + n1;
  ushort* Bpk = Ob + n1;  // 4 x 512KB fragment-packed weights

  prep_kernel<<<dim3(256), 256, 0, stream>>>(wq, wk, wv, wo, Bpk);
  gemm_qkv<<<dim3(384), 512, 0, stream>>>(q, k, v, Bpk, bq, bk, bv, Qp, Kp,
                                          VT);
  attn_kernel<<<dim3(kS / 32, 32), 64, 0, stream>>>(Qp, Kp, VT, Ob);
  gemm_out<<<dim3(256), 512, 0, stream>>>(Ob, Bpk, bo, out);
}

// Round 5
// 155.345 us; speedup vs baseline: 1.3443x; 1.0075x over previous
//
#include <hip/hip_runtime.h>

typedef unsigned int uint;
typedef unsigned short ushort;
typedef __attribute__((ext_vector_type(8))) short bf16x8;
typedef __attribute__((ext_vector_type(4))) float f32x4;

namespace {
constexpr int kS = 2048;
constexpr int kD = 512;
constexpr int kH = 8;
constexpr int kBand = 16;

// Workspace offsets (ushort units).
constexpr size_t kQpk = 0;                    // 32 bh x 128 g x 2 kc x 512
constexpr size_t kKpk = 4194304;              // 32 bh x 130 g x 2 kc x 512
constexpr size_t kVpk = kKpk + 4259840;       // 32 bh x 65 gg x 4 nt x 512
constexpr size_t kObp = kVpk + 4259840;       // packed like Apk, 8192 rows
constexpr size_t kApk = kObp + 4194304;       // 3 x 8192 rows x 512
constexpr size_t kBpk = kApk + 12582912;      // 4 z x 8 c x 16 it x 2048
}  // namespace

static __device__ __forceinline__ ushort f2bf(float f) {
  uint u = __builtin_bit_cast(uint, f);
  u = (u + 0x7fffu + ((u >> 16) & 1u)) >> 16;  // RNE
  return (ushort)u;
}

// 8 fp32 -> bf16x8 via v_cvt_pk_bf16_f32 (RNE; bit-identical to f2bf).
static __device__ __forceinline__ bf16x8 cvt8(f32x4 lo, f32x4 hi) {
  uint4 r;
  asm("v_cvt_pk_bf16_f32 %0, %1, %2" : "=v"(r.x) : "v"(lo[0]), "v"(lo[1]));
  asm("v_cvt_pk_bf16_f32 %0, %1, %2" : "=v"(r.y) : "v"(lo[2]), "v"(lo[3]));
  asm("v_cvt_pk_bf16_f32 %0, %1, %2" : "=v"(r.z) : "v"(hi[0]), "v"(hi[1]));
  asm("v_cvt_pk_bf16_f32 %0, %1, %2" : "=v"(r.w) : "v"(hi[2]), "v"(hi[3]));
  return __builtin_bit_cast(bf16x8, r);
}

// ---------------------------------------------------------------------------
// Fragment-packed layouts. For a [rows][512] operand consumed as MFMA frags:
//   frag group (rt=row/64, it=k/32, mi=(row/16)&3): 512 ushorts, addressed
//   base + ((rt*16+it)*4+mi)*512 + lane*8, lane = (k>>3 & 3)*16 + (row&15).
//   => one dwordx4 per lane = 1KB contiguous per wave.  [Apk / Obpk]
// Weights Bpk (from r4, verified): ((z*8+c)*16+it)*2048 + (ni*64+lane)*8,
//   element W[k][n]: c=n>>6, ni=(n>>4)&3, rowlane=n&15, k-part as above.
// Qpk/Kpk: per (bh, g=s>>4, kc=dl>>5): 512 ushorts, lane=(dl>>3&3)*16+(s&15).
//   Kpk has +1 group pad at each end (130 groups).
// Vpk: per (bh, gg=(s+16)>>5, nt=dl>>4): 512 ushorts,
//   lane = (khat>>3)*16 + (dl&15), khat = (s+16)&31, elem = khat&7.
// ---------------------------------------------------------------------------

// ---------------------------------------------------------------------------
// prep_all: [0,384): q/k/v fp32 -> Apk bf16 packed (64 tokens/block).
//           [384,640): weights -> Bpk packed (r4-verified math).
//           [640,704): zero-fill Vpk pad groups (gg=0 low half, gg=64 high).
// ---------------------------------------------------------------------------
__global__ __launch_bounds__(256) void prep_all(
    const float* __restrict__ q, const float* __restrict__ k,
    const float* __restrict__ v, const float* __restrict__ wq,
    const float* __restrict__ wk, const float* __restrict__ wv,
    const float* __restrict__ wo, ushort* __restrict__ ws) {
  __shared__ float Ws[64][65];
  const int blk = blockIdx.x, tid = threadIdx.x;
  if (blk < 384) {  // ---- A packing ----
    const int z = blk >> 7, rb = blk & 127;
    const float* X = z == 0 ? q : (z == 1 ? k : v);
    ushort* A = ws + kApk + (size_t)z * 4194304 + (size_t)rb * 32768;
    const int tl = tid >> 2, dq = tid & 3;
    const float* src = X + (size_t)(rb * 64 + tl) * kD + dq * 8;
    ushort* dstb = A + (tl >> 4) * 512 + (dq * 16 + (tl & 15)) * 8;
#pragma unroll
    for (int c = 0; c < 16; ++c) {
      const f32x4 lo = *(const f32x4*)(src + c * 32);
      const f32x4 hi = *(const f32x4*)(src + c * 32 + 4);
      *(bf16x8*)(dstb + c * 2048) = cvt8(lo, hi);
    }
    return;
  }
  if (blk >= 640) {  // ---- Vpk pad zero-fill ----
    const int idx = blk - 640;  // 0..63
    const int bh = idx >> 1, gg = (idx & 1) * 64;
    ushort* p = ws + kVpk + ((size_t)(bh * 65 + gg) * 4) * 512 + tid * 8;
    *(uint4*)p = (uint4){0, 0, 0, 0};
    return;
  }
  // ---- weight packing ----
  const int w = blk - 384;  // 0..255
  const int z = w >> 6;
  const float* W = z == 0 ? wq : (z == 1 ? wk : (z == 2 ? wv : wo));
  const int kt = ((w >> 3) & 7) * 64, nt = (w & 7) * 64;
  const int r = tid >> 2, c0 = (tid & 3) * 16;
#pragma unroll
  for (int i = 0; i < 4; ++i) {
    const float4 x =
        *(const float4*)(W + (size_t)(kt + r) * kD + nt + c0 + i * 4);
    Ws[r][c0 + i * 4 + 0] = x.x;
    Ws[r][c0 + i * 4 + 1] = x.y;
    Ws[r][c0 + i * 4 + 2] = x.z;
    Ws[r][c0 + i * 4 + 3] = x.w;
  }
  __syncthreads();
  const int nl = tid >> 2, k0 = (tid & 3) * 16;
  alignas(16) ushort tmp[16];
#pragma unroll
  for (int i = 0; i < 16; ++i) tmp[i] = f2bf(Ws[k0 + i][nl]);
  const int ng = nt + nl, kg = kt + k0;
  const int c = ng >> 6, sub = (ng >> 4) & 3, l = ng & 15;
  const int it = kg >> 5, q0 = (kg >> 3) & 3;  // q0 in {0,2}
  ushort* base = ws + kBpk + ((size_t)(z * 8 + c) * 16 + it) * 2048 +
                 (sub * 64 + l) * 8;
  *(uint4*)(base + q0 * 128) = *(const uint4*)&tmp[0];
  *(uint4*)(base + (q0 + 1) * 128) = *(const uint4*)&tmp[8];
}

// ---------------------------------------------------------------------------
// QKV GEMM, barrier-free fragment-packed: one wave per 64x64 tile. All loads
// are 1KB-contiguous dwordx4 bursts; 3 frag sets give 2-deep prefetch; no
// LDS in the K-loop, no s_barrier. Epilogue packs Q/K/V for attn.
// grid 3072: xcd=lin&7, j=lin>>3, ct=j&7, rtl=xcd+8*(j>>3); the 8 col-tiles
// of a row-tile share an XCD + dispatch window (A L2-hit 7x).
// ---------------------------------------------------------------------------
__global__ __launch_bounds__(64) void gemm_qkv(
    const ushort* __restrict__ ws_c, ushort* __restrict__ ws,
    const float* __restrict__ bq, const float* __restrict__ bk,
    const float* __restrict__ bv) {
  __shared__ alignas(16) ushort Tl[64 * 72];

  const int lane = threadIdx.x, l15 = lane & 15, qd = lane >> 4;
  const int lin = blockIdx.x;
  const int xcd = lin & 7, j = lin >> 3;
  const int ct = j & 7;
  const int rtl = xcd + 8 * (j >> 3);  // 0..383
  const int mode = rtl >> 7, rt = rtl & 127;
  const int row0 = rt * 64;

  const float* bias = mode == 0 ? bq : (mode == 1 ? bk : bv);
  const ushort* pa =
      ws_c + kApk + (size_t)mode * 4194304 + (size_t)rt * 32768 + lane * 8;
  const ushort* pb =
      ws_c + kBpk + ((size_t)(mode * 8 + ct) * 16) * 2048 + lane * 8;

  f32x4 acc[4][4];
#pragma unroll
  for (int mi = 0; mi < 4; ++mi)
#pragma unroll
    for (int ni = 0; ni < 4; ++ni) acc[mi][ni] = (f32x4)(0.f);

  bf16x8 Af[3][4], Bf[3][4];
#define LDSET(s, itv)                                                  \
  {                                                                    \
    _Pragma("unroll") for (int x = 0; x < 4; ++x) {                    \
      Af[s][x] = *(const bf16x8*)(pa + (itv)*2048 + x * 512);          \
      Bf[s][x] = *(const bf16x8*)(pb + (itv)*2048 + x * 512);          \
    }                                                                  \
  }
  LDSET(0, 0);
  LDSET(1, 1);
#pragma unroll
  for (int it = 0; it < 16; ++it) {
    if (it < 14) LDSET((it + 2) % 3, it + 2);
    const int s = it % 3;
#pragma unroll
    for (int mi = 0; mi < 4; ++mi)
#pragma unroll
      for (int ni = 0; ni < 4; ++ni)
        acc[mi][ni] = __builtin_amdgcn_mfma_f32_16x16x32_bf16(
            Af[s][mi], Bf[s][ni], acc[mi][ni], 0, 0, 0);
  }
#undef LDSET

  float bcol[4];
#pragma unroll
  for (int ni = 0; ni < 4; ++ni) bcol[ni] = bias[ct * 64 + ni * 16 + l15];

  const int bh = (row0 >> 11) * kH + ct;  // b*8 + h (head == col-tile)
  if (mode <= 1) {  // transpose to [token_local][dlocal], store packed Q/K
#pragma unroll
    for (int mi = 0; mi < 4; ++mi)
#pragma unroll
      for (int ni = 0; ni < 4; ++ni)
#pragma unroll
        for (int r = 0; r < 4; ++r)
          Tl[(mi * 16 + qd * 4 + r) * 72 + ni * 16 + l15] =
              f2bf(acc[mi][ni][r] + bcol[ni]);
    asm volatile("s_waitcnt lgkmcnt(0)" ::: "memory");
    const int s = (row0 & (kS - 1)) + lane;  // in-batch position
    const int g = s >> 4;
    const ushort* Trow = &Tl[lane * 72];
    ushort* base =
        (mode == 0)
            ? ws + kQpk + ((size_t)(bh * 128 + g) * 2) * 512 + (s & 15) * 8
            : ws + kKpk + ((size_t)(bh * 130 + g + 1) * 2) * 512 + (s & 15) * 8;
#pragma unroll
    for (int cc = 0; cc < 8; ++cc)
      *(uint4*)(base + (cc >> 2) * 512 + (cc & 3) * 128) =
          *(const uint4*)&Trow[cc * 8];
  } else {  // mode 2: transpose to [dlocal][token_local], store packed V
#pragma unroll
    for (int mi = 0; mi < 4; ++mi)
#pragma unroll
      for (int ni = 0; ni < 4; ++ni)
#pragma unroll
        for (int r = 0; r < 4; ++r)
          Tl[(ni * 16 + l15) * 72 + mi * 16 + qd * 4 + r] =
              f2bf(acc[mi][ni][r] + bcol[ni]);
    asm volatile("s_waitcnt lgkmcnt(0)" ::: "memory");
    const int nt = lane >> 4, l15v = lane & 15;
    const int sb = (row0 & (kS - 1)) + 16;
    const ushort* Trow = &Tl[lane * 72];
#pragma unroll
    for (int cc = 0; cc < 8; ++cc) {
      const int sc = sb + cc * 8;
      const int gg = sc >> 5, khc = (sc >> 3) & 3;
      ushort* dst = ws + kVpk + ((size_t)(bh * 65 + gg) * 4 + nt) * 512 +
                    khc * 128 + l15v * 8;
      *(uint4*)dst = *(const uint4*)&Trow[cc * 8];
    }
  }
}

// ---------------------------------------------------------------------------
// MFMA banded attention on packed Q/K/V. One wave per 32-query tile per
// (b,h); every operand load is a 1KB-contiguous dwordx4. Output written
// fragment-packed (Obpk) for the out-projection GEMM.
// ---------------------------------------------------------------------------
__global__ __launch_bounds__(64, 2) void attn_kernel(
    const ushort* __restrict__ ws_c, ushort* __restrict__ ws) {
  __shared__ alignas(16) ushort Pl[32 * 72];

  const int lane = threadIdx.x, l15 = lane & 15, qd = lane >> 4;
  const int bh = blockIdx.y;
  const int q0 = blockIdx.x * 32;
  const ushort* Qpk = ws_c + kQpk;
  const ushort* Kpk = ws_c + kKpk;
  const ushort* Vpk = ws_c + kVpk;

  bf16x8 qf[2][2], kf[4][2];
#pragma unroll
  for (int mi = 0; mi < 2; ++mi)
#pragma unroll
    for (int kc = 0; kc < 2; ++kc)
      qf[mi][kc] = *(const bf16x8*)&Qpk[((size_t)(bh * 128 + (q0 >> 4) + mi) *
                                            2 + kc) * 512 + lane * 8];
#pragma unroll
  for (int ni = 0; ni < 4; ++ni)
#pragma unroll
    for (int kc = 0; kc < 2; ++kc)
      kf[ni][kc] = *(const bf16x8*)&Kpk[((size_t)(bh * 130 + (q0 >> 4) + ni) *
                                            2 + kc) * 512 + lane * 8];

  f32x4 S[2][4];
#pragma unroll
  for (int mi = 0; mi < 2; ++mi)
#pragma unroll
    for (int ni = 0; ni < 4; ++ni) S[mi][ni] = (f32x4)(0.f);
#pragma unroll
  for (int mi = 0; mi < 2; ++mi)
#pragma unroll
    for (int ni = 0; ni < 4; ++ni)
#pragma unroll
      for (int kc = 0; kc < 2; ++kc)
        S[mi][ni] = __builtin_amdgcn_mfma_f32_16x16x32_bf16(
            qf[mi][kc], kf[ni][kc], S[mi][ni], 0, 0, 0);

#pragma unroll
  for (int mi = 0; mi < 2; ++mi)
#pragma unroll
    for (int ni = 0; ni < 4; ++ni)
#pragma unroll
      for (int r = 0; r < 4; ++r) {
        const int q_local = mi * 16 + qd * 4 + r;
        const int key_local = ni * 16 + l15;
        const int key = q0 - kBand + key_local;
        const int dlt = key_local - q_local;
        const bool ok = (dlt >= 0) && (dlt <= 32) && (key >= 0) && (key < kS);
        S[mi][ni][r] = ok ? S[mi][ni][r] * 0.125f : -3.0e38f;
      }

  float inv[2][4];
#pragma unroll
  for (int mi = 0; mi < 2; ++mi)
#pragma unroll
    for (int r = 0; r < 4; ++r) {
      float m = S[mi][0][r];
#pragma unroll
      for (int ni = 1; ni < 4; ++ni) m = fmaxf(m, S[mi][ni][r]);
      m = fmaxf(m, __shfl_xor(m, 1));
      m = fmaxf(m, __shfl_xor(m, 2));
      m = fmaxf(m, __shfl_xor(m, 4));
      m = fmaxf(m, __shfl_xor(m, 8));
      float s = 0.f;
#pragma unroll
      for (int ni = 0; ni < 4; ++ni) {
        const float e = __expf(S[mi][ni][r] - m);
        S[mi][ni][r] = e;
        s += e;
      }
      s += __shfl_xor(s, 1);
      s += __shfl_xor(s, 2);
      s += __shfl_xor(s, 4);
      s += __shfl_xor(s, 8);
      inv[mi][r] = 1.f / s;
    }

  // P -> LDS (C-layout scatter, stride 72), read back in A-layout
#pragma unroll
  for (int mi = 0; mi < 2; ++mi)
#pragma unroll
    for (int ni = 0; ni < 4; ++ni)
#pragma unroll
      for (int r = 0; r < 4; ++r)
        Pl[(mi * 16 + qd * 4 + r) * 72 + ni * 16 + l15] = f2bf(S[mi][ni][r]);
  __syncthreads();

  f32x4 O[2][4];
#pragma unroll
  for (int mi = 0; mi < 2; ++mi)
#pragma unroll
    for (int nt = 0; nt < 4; ++nt) O[mi][nt] = (f32x4)(0.f);

#pragma unroll
  for (int kc = 0; kc < 2; ++kc) {
    bf16x8 pf[2], vfr[4];
#pragma unroll
    for (int mi = 0; mi < 2; ++mi)
      pf[mi] = *(const bf16x8*)&Pl[(mi * 16 + l15) * 72 + kc * 32 + qd * 8];
#pragma unroll
    for (int nt = 0; nt < 4; ++nt)
      vfr[nt] = *(const bf16x8*)&Vpk[((size_t)(bh * 65 + (q0 >> 5) + kc) * 4 +
                                       nt) * 512 + lane * 8];
#pragma unroll
    for (int mi = 0; mi < 2; ++mi)
#pragma unroll
      for (int nt = 0; nt < 4; ++nt)
        O[mi][nt] = __builtin_amdgcn_mfma_f32_16x16x32_bf16(pf[mi], vfr[nt],
                                                            O[mi][nt], 0, 0, 0);
  }

  // O transpose through LDS (reuse Pl; same-wave DS ops are in-order)
#pragma unroll
  for (int mi = 0; mi < 2; ++mi)
#pragma unroll
    for (int nt = 0; nt < 4; ++nt)
#pragma unroll
      for (int r = 0; r < 4; ++r)
        Pl[(mi * 16 + qd * 4 + r) * 72 + nt * 16 + l15] =
            f2bf(O[mi][nt][r] * inv[mi][r]);
  asm volatile("s_waitcnt lgkmcnt(0)" ::: "memory");

  // Store fragment-packed Obpk: 2 lanes/token, 4 x 16B chunks each.
  const int row = lane >> 1, half = lane & 1;
  const int tglob = (bh >> 3) * kS + q0 + row;
  const int rt = tglob >> 6, mi2 = (tglob >> 4) & 3, l15o = tglob & 15;
  const int h = bh & 7;
  ushort* Obp = ws + kObp;
#pragma unroll
  for (int jj = 0; jj < 4; ++jj) {
    const int cc = half * 4 + jj;
    const int it2 = h * 2 + (cc >> 2), qd2 = cc & 3;
    ushort* dst = Obp + ((size_t)(rt * 16 + it2) * 4 + mi2) * 512 +
                  (qd2 * 16 + l15o) * 8;
    *(uint4*)dst = *(const uint4*)&Pl[row * 72 + cc * 8];
  }
}

// ---------------------------------------------------------------------------
// Out-projection GEMM: same barrier-free packed structure; A = Obpk,
// B = Bpk mode 3; fp32 direct stores + bias. grid 1024.
// ---------------------------------------------------------------------------
__global__ __launch_bounds__(64) void gemm_out(
    const ushort* __restrict__ ws_c, const float* __restrict__ bo,
    float* __restrict__ outp) {
  const int lane = threadIdx.x, l15 = lane & 15, qd = lane >> 4;
  const int lin = blockIdx.x;
  const int xcd = lin & 7, j = lin >> 3;
  const int ct = j & 7;
  const int rt = xcd + 8 * (j >> 3);  // 0..127
  const int row0 = rt * 64;

  const ushort* pa = ws_c + kObp + (size_t)rt * 32768 + lane * 8;
  const ushort* pb =
      ws_c + kBpk + ((size_t)(3 * 8 + ct) * 16) * 2048 + lane * 8;

  f32x4 acc[4][4];
#pragma unroll
  for (int mi = 0; mi < 4; ++mi)
#pragma unroll
    for (int ni = 0; ni < 4; ++ni) acc[mi][ni] = (f32x4)(0.f);

  bf16x8 Af[3][4], Bf[3][4];
#define LDSET(s, itv)                                                  \
  {                                                                    \
    _Pragma("unroll") for (int x = 0; x < 4; ++x) {                    \
      Af[s][x] = *(const bf16x8*)(pa + (itv)*2048 + x * 512);          \
      Bf[s][x] = *(const bf16x8*)(pb + (itv)*2048 + x * 512);          \
    }                                                                  \
  }
  LDSET(0, 0);
  LDSET(1, 1);
#pragma unroll
  for (int it = 0; it < 16; ++it) {
    if (it < 14) LDSET((it + 2) % 3, it + 2);
    const int s = it % 3;
#pragma unroll
    for (int mi = 0; mi < 4; ++mi)
#pragma unroll
      for (int ni = 0; ni < 4; ++ni)
        acc[mi][ni] = __builtin_amdgcn_mfma_f32_16x16x32_bf16(
            Af[s][mi], Bf[s][ni], acc[mi][ni], 0, 0, 0);
  }
#undef LDSET

#pragma unroll
  for (int ni = 0; ni < 4; ++ni) {
    const int colg = ct * 64 + ni * 16 + l15;
    const float bc = bo[colg];
#pragma unroll
    for (int mi = 0; mi < 4; ++mi)
#pragma unroll
      for (int r = 0; r < 4; ++r) {
        const int token = row0 + mi * 16 + qd * 4 + r;
        outp[(size_t)token * kD + colg] = acc[mi][ni][r] + bc;
      }
  }
}

extern "C" void kernel_launch(void* const* d_in, const int* in_sizes, int n_in,
                              void* d_out, int out_size, void* d_ws,
                              size_t ws_size, hipStream_t stream) {
  const float* q = (const float*)d_in[0];
  const float* k = (const float*)d_in[1];
  const float* v = (const float*)d_in[2];
  const float* wq = (const float*)d_in[3];
  const float* bq = (const float*)d_in[4];
  const float* wk = (const float*)d_in[5];
  const float* bk = (const float*)d_in[6];
  const float* wv = (const float*)d_in[7];
  const float* bv = (const float*)d_in[8];
  const float* wo = (const float*)d_in[9];
  const float* bo = (const float*)d_in[10];
  float* out = (float*)d_out;

  ushort* ws = (ushort*)d_ws;  // ~61 MB, offsets in kQpk..kBpk

  prep_all<<<dim3(704), 256, 0, stream>>>(q, k, v, wq, wk, wv, wo, ws);
  gemm_qkv<<<dim3(3072), 64, 0, stream>>>(ws, ws, bq, bk, bv);
  attn_kernel<<<dim3(kS / 32, 32), 64, 0, stream>>>(ws, ws);
  gemm_out<<<dim3(1024), 64, 0, stream>>>(ws, bo, out);
}

// Round 6
// 149.085 us; speedup vs baseline: 1.4007x; 1.0420x over previous
//
#include <hip/hip_runtime.h>

typedef unsigned int uint;
typedef unsigned short ushort;
typedef __attribute__((ext_vector_type(8))) short bf16x8;
typedef __attribute__((ext_vector_type(4))) float f32x4;

namespace {
constexpr int kS = 2048;
constexpr int kD = 512;
constexpr int kH = 8;
constexpr int kBand = 16;

// Workspace offsets (ushort units). (kObp slot retained but unused.)
constexpr size_t kQpk = 0;                    // 32 bh x 128 g x 2 kc x 512
constexpr size_t kKpk = 4194304;              // 32 bh x 130 g x 2 kc x 512
constexpr size_t kVpk = kKpk + 4259840;       // 32 bh x 65 gg x 4 nt x 512
constexpr size_t kObp = kVpk + 4259840;       // (unused after attn+out fusion)
constexpr size_t kApk = kObp + 4194304;       // 3 x 8192 rows x 512
constexpr size_t kBpk = kApk + 12582912;      // 4 z x 8 c x 16 it x 2048
}  // namespace

static __device__ __forceinline__ ushort f2bf(float f) {
  uint u = __builtin_bit_cast(uint, f);
  u = (u + 0x7fffu + ((u >> 16) & 1u)) >> 16;  // RNE
  return (ushort)u;
}

// 8 fp32 -> bf16x8 via v_cvt_pk_bf16_f32 (RNE; bit-identical to f2bf).
static __device__ __forceinline__ bf16x8 cvt8(f32x4 lo, f32x4 hi) {
  uint4 r;
  asm("v_cvt_pk_bf16_f32 %0, %1, %2" : "=v"(r.x) : "v"(lo[0]), "v"(lo[1]));
  asm("v_cvt_pk_bf16_f32 %0, %1, %2" : "=v"(r.y) : "v"(lo[2]), "v"(lo[3]));
  asm("v_cvt_pk_bf16_f32 %0, %1, %2" : "=v"(r.z) : "v"(hi[0]), "v"(hi[1]));
  asm("v_cvt_pk_bf16_f32 %0, %1, %2" : "=v"(r.w) : "v"(hi[2]), "v"(hi[3]));
  return __builtin_bit_cast(bf16x8, r);
}

// ---------------------------------------------------------------------------
// prep_all: [0,384): q/k/v fp32 -> Apk bf16 packed (64 tokens/block).
//           [384,640): weights -> Bpk packed.
//           [640,704): zero-fill Vpk pad groups.
// ---------------------------------------------------------------------------
__global__ __launch_bounds__(256) void prep_all(
    const float* __restrict__ q, const float* __restrict__ k,
    const float* __restrict__ v, const float* __restrict__ wq,
    const float* __restrict__ wk, const float* __restrict__ wv,
    const float* __restrict__ wo, ushort* __restrict__ ws) {
  __shared__ float Ws[64][65];
  const int blk = blockIdx.x, tid = threadIdx.x;
  if (blk < 384) {  // ---- A packing ----
    const int z = blk >> 7, rb = blk & 127;
    const float* X = z == 0 ? q : (z == 1 ? k : v);
    ushort* A = ws + kApk + (size_t)z * 4194304 + (size_t)rb * 32768;
    const int tl = tid >> 2, dq = tid & 3;
    const float* src = X + (size_t)(rb * 64 + tl) * kD + dq * 8;
    ushort* dstb = A + (tl >> 4) * 512 + (dq * 16 + (tl & 15)) * 8;
#pragma unroll
    for (int c = 0; c < 16; ++c) {
      const f32x4 lo = *(const f32x4*)(src + c * 32);
      const f32x4 hi = *(const f32x4*)(src + c * 32 + 4);
      *(bf16x8*)(dstb + c * 2048) = cvt8(lo, hi);
    }
    return;
  }
  if (blk >= 640) {  // ---- Vpk pad zero-fill ----
    const int idx = blk - 640;  // 0..63
    const int bh = idx >> 1, gg = (idx & 1) * 64;
    ushort* p = ws + kVpk + ((size_t)(bh * 65 + gg) * 4) * 512 + tid * 8;
    *(uint4*)p = (uint4){0, 0, 0, 0};
    return;
  }
  // ---- weight packing ----
  const int w = blk - 384;  // 0..255
  const int z = w >> 6;
  const float* W = z == 0 ? wq : (z == 1 ? wk : (z == 2 ? wv : wo));
  const int kt = ((w >> 3) & 7) * 64, nt = (w & 7) * 64;
  const int r = tid >> 2, c0 = (tid & 3) * 16;
#pragma unroll
  for (int i = 0; i < 4; ++i) {
    const float4 x =
        *(const float4*)(W + (size_t)(kt + r) * kD + nt + c0 + i * 4);
    Ws[r][c0 + i * 4 + 0] = x.x;
    Ws[r][c0 + i * 4 + 1] = x.y;
    Ws[r][c0 + i * 4 + 2] = x.z;
    Ws[r][c0 + i * 4 + 3] = x.w;
  }
  __syncthreads();
  const int nl = tid >> 2, k0 = (tid & 3) * 16;
  alignas(16) ushort tmp[16];
#pragma unroll
  for (int i = 0; i < 16; ++i) tmp[i] = f2bf(Ws[k0 + i][nl]);
  const int ng = nt + nl, kg = kt + k0;
  const int c = ng >> 6, sub = (ng >> 4) & 3, l = ng & 15;
  const int it = kg >> 5, q0 = (kg >> 3) & 3;  // q0 in {0,2}
  ushort* base = ws + kBpk + ((size_t)(z * 8 + c) * 16 + it) * 2048 +
                 (sub * 64 + l) * 8;
  *(uint4*)(base + q0 * 128) = *(const uint4*)&tmp[0];
  *(uint4*)(base + (q0 + 1) * 128) = *(const uint4*)&tmp[8];
}

// ---------------------------------------------------------------------------
// QKV GEMM, barrier-free fragment-packed: one wave per 64x64 tile. All loads
// are 1KB-contiguous dwordx4 bursts; 3 frag sets give 2-deep prefetch; no
// LDS in the K-loop, no s_barrier. Epilogue packs Q/K/V for attn.
// ---------------------------------------------------------------------------
__global__ __launch_bounds__(64) void gemm_qkv(
    const ushort* __restrict__ ws_c, ushort* __restrict__ ws,
    const float* __restrict__ bq, const float* __restrict__ bk,
    const float* __restrict__ bv) {
  __shared__ alignas(16) ushort Tl[64 * 72];

  const int lane = threadIdx.x, l15 = lane & 15, qd = lane >> 4;
  const int lin = blockIdx.x;
  const int xcd = lin & 7, j = lin >> 3;
  const int ct = j & 7;
  const int rtl = xcd + 8 * (j >> 3);  // 0..383
  const int mode = rtl >> 7, rt = rtl & 127;
  const int row0 = rt * 64;

  const float* bias = mode == 0 ? bq : (mode == 1 ? bk : bv);
  const ushort* pa =
      ws_c + kApk + (size_t)mode * 4194304 + (size_t)rt * 32768 + lane * 8;
  const ushort* pb =
      ws_c + kBpk + ((size_t)(mode * 8 + ct) * 16) * 2048 + lane * 8;

  f32x4 acc[4][4];
#pragma unroll
  for (int mi = 0; mi < 4; ++mi)
#pragma unroll
    for (int ni = 0; ni < 4; ++ni) acc[mi][ni] = (f32x4)(0.f);

  bf16x8 Af[3][4], Bf[3][4];
#define LDSET(s, itv)                                                  \
  {                                                                    \
    _Pragma("unroll") for (int x = 0; x < 4; ++x) {                    \
      Af[s][x] = *(const bf16x8*)(pa + (itv)*2048 + x * 512);          \
      Bf[s][x] = *(const bf16x8*)(pb + (itv)*2048 + x * 512);          \
    }                                                                  \
  }
  LDSET(0, 0);
  LDSET(1, 1);
#pragma unroll
  for (int it = 0; it < 16; ++it) {
    if (it < 14) LDSET((it + 2) % 3, it + 2);
    const int s = it % 3;
#pragma unroll
    for (int mi = 0; mi < 4; ++mi)
#pragma unroll
      for (int ni = 0; ni < 4; ++ni)
        acc[mi][ni] = __builtin_amdgcn_mfma_f32_16x16x32_bf16(
            Af[s][mi], Bf[s][ni], acc[mi][ni], 0, 0, 0);
  }
#undef LDSET

  float bcol[4];
#pragma unroll
  for (int ni = 0; ni < 4; ++ni) bcol[ni] = bias[ct * 64 + ni * 16 + l15];

  const int bh = (row0 >> 11) * kH + ct;  // b*8 + h (head == col-tile)
  if (mode <= 1) {  // transpose to [token_local][dlocal], store packed Q/K
#pragma unroll
    for (int mi = 0; mi < 4; ++mi)
#pragma unroll
      for (int ni = 0; ni < 4; ++ni)
#pragma unroll
        for (int r = 0; r < 4; ++r)
          Tl[(mi * 16 + qd * 4 + r) * 72 + ni * 16 + l15] =
              f2bf(acc[mi][ni][r] + bcol[ni]);
    asm volatile("s_waitcnt lgkmcnt(0)" ::: "memory");
    const int s = (row0 & (kS - 1)) + lane;  // in-batch position
    const int g = s >> 4;
    const ushort* Trow = &Tl[lane * 72];
    ushort* base =
        (mode == 0)
            ? ws + kQpk + ((size_t)(bh * 128 + g) * 2) * 512 + (s & 15) * 8
            : ws + kKpk + ((size_t)(bh * 130 + g + 1) * 2) * 512 + (s & 15) * 8;
#pragma unroll
    for (int cc = 0; cc < 8; ++cc)
      *(uint4*)(base + (cc >> 2) * 512 + (cc & 3) * 128) =
          *(const uint4*)&Trow[cc * 8];
  } else {  // mode 2: transpose to [dlocal][token_local], store packed V
#pragma unroll
    for (int mi = 0; mi < 4; ++mi)
#pragma unroll
      for (int ni = 0; ni < 4; ++ni)
#pragma unroll
        for (int r = 0; r < 4; ++r)
          Tl[(ni * 16 + l15) * 72 + mi * 16 + qd * 4 + r] =
              f2bf(acc[mi][ni][r] + bcol[ni]);
    asm volatile("s_waitcnt lgkmcnt(0)" ::: "memory");
    const int nt = lane >> 4, l15v = lane & 15;
    const int sb = (row0 & (kS - 1)) + 16;
    const ushort* Trow = &Tl[lane * 72];
#pragma unroll
    for (int cc = 0; cc < 8; ++cc) {
      const int sc = sb + cc * 8;
      const int gg = sc >> 5, khc = (sc >> 3) & 3;
      ushort* dst = ws + kVpk + ((size_t)(bh * 65 + gg) * 4 + nt) * 512 +
                    khc * 128 + l15v * 8;
      *(uint4*)dst = *(const uint4*)&Trow[cc * 8];
    }
  }
}

// ---------------------------------------------------------------------------
// FUSED attention + out-projection. Block = 512 threads = 8 waves = 8 heads
// of one (b, 32-query tile). Each wave runs the (verified) banded-attn body
// into its own Pl slice [32][72] — which is already [token][d] layout — then
// after ONE barrier, each wave computes a 32x64 slice of O @ Wo + bo reading
// A-fragments straight from the 8 Pl slices (144 B/row => <=2-way bank
// aliasing, free) and B from the L2-resident packed Wo. fp32 direct stores.
// Removes Obpk round-trip + gemm_out kernel entirely. grid (64, 4).
// ---------------------------------------------------------------------------
__global__ __launch_bounds__(512) void attn_out(
    const ushort* __restrict__ ws_c, const float* __restrict__ bo,
    float* __restrict__ outp) {
  __shared__ alignas(16) ushort Pl[8 * 32 * 72];  // per-wave slices

  const int tid = threadIdx.x;
  const int w = tid >> 6, lane = tid & 63, l15 = lane & 15, qd = lane >> 4;
  const int b = blockIdx.y;
  const int q0 = blockIdx.x * 32;
  const int bh = b * kH + w;  // wave == head
  ushort* Plw = &Pl[w * 2304];

  const ushort* Qpk = ws_c + kQpk;
  const ushort* Kpk = ws_c + kKpk;
  const ushort* Vpk = ws_c + kVpk;

  // ---- attention phase (r5-verified math) ----
  bf16x8 qf[2][2], kf[4][2];
#pragma unroll
  for (int mi = 0; mi < 2; ++mi)
#pragma unroll
    for (int kc = 0; kc < 2; ++kc)
      qf[mi][kc] = *(const bf16x8*)&Qpk[((size_t)(bh * 128 + (q0 >> 4) + mi) *
                                            2 + kc) * 512 + lane * 8];
#pragma unroll
  for (int ni = 0; ni < 4; ++ni)
#pragma unroll
    for (int kc = 0; kc < 2; ++kc)
      kf[ni][kc] = *(const bf16x8*)&Kpk[((size_t)(bh * 130 + (q0 >> 4) + ni) *
                                            2 + kc) * 512 + lane * 8];

  f32x4 S[2][4];
#pragma unroll
  for (int mi = 0; mi < 2; ++mi)
#pragma unroll
    for (int ni = 0; ni < 4; ++ni) S[mi][ni] = (f32x4)(0.f);
#pragma unroll
  for (int mi = 0; mi < 2; ++mi)
#pragma unroll
    for (int ni = 0; ni < 4; ++ni)
#pragma unroll
      for (int kc = 0; kc < 2; ++kc)
        S[mi][ni] = __builtin_amdgcn_mfma_f32_16x16x32_bf16(
            qf[mi][kc], kf[ni][kc], S[mi][ni], 0, 0, 0);

#pragma unroll
  for (int mi = 0; mi < 2; ++mi)
#pragma unroll
    for (int ni = 0; ni < 4; ++ni)
#pragma unroll
      for (int r = 0; r < 4; ++r) {
        const int q_local = mi * 16 + qd * 4 + r;
        const int key_local = ni * 16 + l15;
        const int key = q0 - kBand + key_local;
        const int dlt = key_local - q_local;
        const bool ok = (dlt >= 0) && (dlt <= 32) && (key >= 0) && (key < kS);
        S[mi][ni][r] = ok ? S[mi][ni][r] * 0.125f : -3.0e38f;
      }

  float inv[2][4];
#pragma unroll
  for (int mi = 0; mi < 2; ++mi)
#pragma unroll
    for (int r = 0; r < 4; ++r) {
      float m = S[mi][0][r];
#pragma unroll
      for (int ni = 1; ni < 4; ++ni) m = fmaxf(m, S[mi][ni][r]);
      m = fmaxf(m, __shfl_xor(m, 1));
      m = fmaxf(m, __shfl_xor(m, 2));
      m = fmaxf(m, __shfl_xor(m, 4));
      m = fmaxf(m, __shfl_xor(m, 8));
      float s = 0.f;
#pragma unroll
      for (int ni = 0; ni < 4; ++ni) {
        const float e = __expf(S[mi][ni][r] - m);
        S[mi][ni][r] = e;
        s += e;
      }
      s += __shfl_xor(s, 1);
      s += __shfl_xor(s, 2);
      s += __shfl_xor(s, 4);
      s += __shfl_xor(s, 8);
      inv[mi][r] = 1.f / s;
    }

  // P -> own Pl slice (C-layout scatter, stride 72), read back in A-layout.
#pragma unroll
  for (int mi = 0; mi < 2; ++mi)
#pragma unroll
    for (int ni = 0; ni < 4; ++ni)
#pragma unroll
      for (int r = 0; r < 4; ++r)
        Plw[(mi * 16 + qd * 4 + r) * 72 + ni * 16 + l15] = f2bf(S[mi][ni][r]);
  asm volatile("s_waitcnt lgkmcnt(0)" ::: "memory");  // wave-local RAW

  f32x4 O[2][4];
#pragma unroll
  for (int mi = 0; mi < 2; ++mi)
#pragma unroll
    for (int nt = 0; nt < 4; ++nt) O[mi][nt] = (f32x4)(0.f);

#pragma unroll
  for (int kc = 0; kc < 2; ++kc) {
    bf16x8 pf[2], vfr[4];
#pragma unroll
    for (int mi = 0; mi < 2; ++mi)
      pf[mi] = *(const bf16x8*)&Plw[(mi * 16 + l15) * 72 + kc * 32 + qd * 8];
#pragma unroll
    for (int nt = 0; nt < 4; ++nt)
      vfr[nt] = *(const bf16x8*)&Vpk[((size_t)(bh * 65 + (q0 >> 5) + kc) * 4 +
                                       nt) * 512 + lane * 8];
#pragma unroll
    for (int mi = 0; mi < 2; ++mi)
#pragma unroll
      for (int nt = 0; nt < 4; ++nt)
        O[mi][nt] = __builtin_amdgcn_mfma_f32_16x16x32_bf16(pf[mi], vfr[nt],
                                                            O[mi][nt], 0, 0, 0);
  }

  // O (scaled) -> own Pl slice as [token_local][d_local], stride 72.
  // Same-wave DS ops are issued in order after the pf reads above.
#pragma unroll
  for (int mi = 0; mi < 2; ++mi)
#pragma unroll
    for (int nt = 0; nt < 4; ++nt)
#pragma unroll
      for (int r = 0; r < 4; ++r)
        Plw[(mi * 16 + qd * 4 + r) * 72 + nt * 16 + l15] =
            f2bf(O[mi][nt][r] * inv[mi][r]);

  __syncthreads();  // all 8 heads' O visible to all waves

  // ---- out-projection phase: wave w computes cols [w*64, w*64+64) ----
  const ushort* pb =
      ws_c + kBpk + ((size_t)(3 * 8 + w) * 16) * 2048 + lane * 8;

  f32x4 acc[2][4];
#pragma unroll
  for (int mi = 0; mi < 2; ++mi)
#pragma unroll
    for (int ni = 0; ni < 4; ++ni) acc[mi][ni] = (f32x4)(0.f);

  bf16x8 Bf[2][4];
#pragma unroll
  for (int x = 0; x < 4; ++x) Bf[0][x] = *(const bf16x8*)(pb + x * 512);
#pragma unroll
  for (int it = 0; it < 16; ++it) {
    if (it < 15) {
#pragma unroll
      for (int x = 0; x < 4; ++x)
        Bf[(it + 1) & 1][x] =
            *(const bf16x8*)(pb + (size_t)(it + 1) * 2048 + x * 512);
    }
    bf16x8 af[2];
#pragma unroll
    for (int mi = 0; mi < 2; ++mi)
      af[mi] = *(const bf16x8*)&Pl[(it >> 1) * 2304 + (mi * 16 + l15) * 72 +
                                   (it & 1) * 32 + qd * 8];
#pragma unroll
    for (int mi = 0; mi < 2; ++mi)
#pragma unroll
      for (int ni = 0; ni < 4; ++ni)
        acc[mi][ni] = __builtin_amdgcn_mfma_f32_16x16x32_bf16(
            af[mi], Bf[it & 1][ni], acc[mi][ni], 0, 0, 0);
  }

#pragma unroll
  for (int ni = 0; ni < 4; ++ni) {
    const int colg = w * 64 + ni * 16 + l15;
    const float bc = bo[colg];
#pragma unroll
    for (int mi = 0; mi < 2; ++mi)
#pragma unroll
      for (int r = 0; r < 4; ++r) {
        const int token = b * kS + q0 + mi * 16 + qd * 4 + r;
        outp[(size_t)token * kD + colg] = acc[mi][ni][r] + bc;
      }
  }
}

extern "C" void kernel_launch(void* const* d_in, const int* in_sizes, int n_in,
                              void* d_out, int out_size, void* d_ws,
                              size_t ws_size, hipStream_t stream) {
  const float* q = (const float*)d_in[0];
  const float* k = (const float*)d_in[1];
  const float* v = (const float*)d_in[2];
  const float* wq = (const float*)d_in[3];
  const float* bq = (const float*)d_in[4];
  const float* wk = (const float*)d_in[5];
  const float* bk = (const float*)d_in[6];
  const float* wv = (const float*)d_in[7];
  const float* bv = (const float*)d_in[8];
  const float* wo = (const float*)d_in[9];
  const float* bo = (const float*)d_in[10];
  float* out = (float*)d_out;

  ushort* ws = (ushort*)d_ws;

  prep_all<<<dim3(704), 256, 0, stream>>>(q, k, v, wq, wk, wv, wo, ws);
  gemm_qkv<<<dim3(3072), 64, 0, stream>>>(ws, ws, bq, bk, bv);
  attn_out<<<dim3(kS / 32, 4), 512, 0, stream>>>(ws, bo, out);
}